// Round 27
// baseline (23.183 us; speedup 1.0000x reference)
//
#include <hip/hip_runtime.h>
#include <math.h>

#define W_ 128
#define H_ 96
#define C_ 128
#define HW_ (H_ * W_)          // 12288
#define K_ 81
#define FLOW_ELEMS (2 * 2 * H_ * W_)   // 49152
#define TCOLS 32               // tile cols allocated; 24 staged (cols 24..31 unused)
#define TSTR 68                // u32 stride per col; 272 B -> 16B-aligned b128 reads

typedef __fp16 f16x8 __attribute__((ext_vector_type(8)));
typedef float  f32x4 __attribute__((ext_vector_type(4)));

__device__ __forceinline__ unsigned pack_pair(float a, float b) {
    return __builtin_bit_cast(unsigned, __builtin_amdgcn_cvt_pkrtz(a, b));
}

// Round 27: champion (R26) with T3/T4 counted-vmcnt barriers. __syncthreads()
// in the phase loop compiles to s_waitcnt vmcnt(0) lgkmcnt(0) + s_barrier --
// draining ALL prefetched global loads every phase (this explains R24's
// 5-deep being exactly neutral). Replaced with: s_waitcnt lgkmcnt(0) (LDS
// visibility only) + raw s_barrier + sched_barrier(0) (rule #18 fence).
// Prefetched vmem loads now stay in flight across barriers; the compiler's
// dep tracking inserts counted vmcnt waits at register use. Barriers remain
// block-uniform (OK depends on y0/p only). Everything else = R26 verbatim.
// Block = 192 thr (3 waves); 512 blocks = 2/CU.
__global__ __launch_bounds__(192) void fused_kernel(const float* __restrict__ f0,
                                                    const float* __restrict__ f1,
                                                    float* __restrict__ out) {
    __shared__ unsigned tile[TCOLS * TSTR];          // 8704 B
    __shared__ float corr_lds[3][16][85];            // 16320 B
    __shared__ float pmax[4][49], psum[4][49], pfxb[4][49], pfyb[4][49];
    __shared__ float ibuf[48];

    const int t = threadIdx.x;
    const int ry = t >> 6, l = t & 63;   // wave id == output row within strip
    const int L = (blockIdx.x & 7) * 64 + (blockIdx.x >> 3);   // 512 = 8*64
    const int b = L >> 8;
    const int rem = L & 255;
    const int ys = rem >> 3, xq = rem & 7;
    const int y0 = ys * 3;               // rows y0, y0+1, y0+2
    const int px0 = xq * 16;             // 16-px tile base

    // ---- staging slots: exactly 2/thread; s = i*192+t: cp = s/6, quad q = s%6 ----
    int g_off[2], lds_w[2];
    bool g_ok[2];
#pragma unroll
    for (int i = 0; i < 2; ++i) {
        const int s = i * 192 + t;
        const int cp = s / 6;
        const int q = s - cp * 6;
        const int x0 = px0 + 4 * q - 4;
        g_ok[i] = (x0 >= 0) && (x0 <= 124);
        g_off[i] = 2 * cp * HW_ + (g_ok[i] ? x0 : 0);
        lds_w[i] = (4 * q) * TSTR + cp;
    }
    const float* f1base = f1 + (size_t)b * C_ * HW_;

    // ---- A-frags (R14-verified layout), row y0+ry, scale folded ----
    const float scale = 0.08838834764831845f;   // 1/sqrt(128)
    f16x8 a[4];
    {
        const float* f0p = f0 + (size_t)b * C_ * HW_ + (size_t)(y0 + ry) * W_
                              + px0 + (l & 15);
#pragma unroll
        for (int kk = 0; kk < 4; ++kk) {
            f16x8 av;
#pragma unroll
            for (int j = 0; j < 8; ++j)
                av[j] = (__fp16)(f0p[(size_t)(kk * 32 + (l >> 4) * 8 + j) * HW_] * scale);
            a[kk] = av;
        }
    }

    // ---- helpers (verified patterns) ----
    auto LOADP = [&](int p, float4 (&va)[2], float4 (&vb)[2], bool& ok) {
        const int r = y0 - 4 + p;
        ok = (r >= 0) && (r < H_);
        const float* f1b = f1base + (size_t)(ok ? r : 0) * W_;
#pragma unroll
        for (int i = 0; i < 2; ++i) {
            float4 x = {0.f, 0.f, 0.f, 0.f}, y = {0.f, 0.f, 0.f, 0.f};
            if (ok && g_ok[i]) {
                x = *(const float4*)(f1b + g_off[i]);
                y = *(const float4*)(f1b + g_off[i] + HW_);
            }
            va[i] = x; vb[i] = y;
        }
    };
    auto WRITEP = [&](const float4 (&va)[2], const float4 (&vb)[2]) {
#pragma unroll
        for (int i = 0; i < 2; ++i) {
            tile[lds_w[i]]            = pack_pair(va[i].x, vb[i].x);
            tile[lds_w[i] + TSTR]     = pack_pair(va[i].y, vb[i].y);
            tile[lds_w[i] + 2 * TSTR] = pack_pair(va[i].z, vb[i].z);
            tile[lds_w[i] + 3 * TSTR] = pack_pair(va[i].w, vb[i].w);
        }
    };
    auto COMPUTE = [&](int dyi) {        // dyi = p - ry in [0,8]
        f32x4 accA = {0.f, 0.f, 0.f, 0.f}, accB = {0.f, 0.f, 0.f, 0.f};
#pragma unroll
        for (int kk = 0; kk < 4; ++kk) {
            const int off = kk * 16 + (l >> 4) * 4;
            {
                const int col = l & 15;
                const uint4 u = *(const uint4*)&tile[col * TSTR + off];  // b128
                accA = __builtin_amdgcn_mfma_f32_16x16x32_f16(
                    a[kk], __builtin_bit_cast(f16x8, u), accA, 0, 0, 0);
            }
            {
                const int col = 16 + (l & 15);   // cols 24..31: outputs discarded
                const uint4 u = *(const uint4*)&tile[col * TSTR + off];  // b128
                accB = __builtin_amdgcn_mfma_f32_16x16x32_f16(
                    a[kk], __builtin_bit_cast(f16x8, u), accB, 0, 0, 0);
            }
        }
        // band extract (R14-verified): dx = j2 - i2 in [0,8]
#pragma unroll
        for (int h = 0; h < 2; ++h) {
            const f32x4 acc = h ? accB : accA;
#pragma unroll
            for (int rg = 0; rg < 4; ++rg) {
                const int i2 = (l >> 4) * 4 + rg;
                const int j2 = h * 16 + (l & 15);
                const int dxw = j2 - i2;
                if (dxw >= 0 && dxw <= 8)
                    corr_lds[ry][i2][dyi * 9 + dxw] = acc[rg];
            }
        }
    };

    float4 vaA[2], vbA[2], vaB[2], vbB[2], vaC[2], vbC[2];
    bool okA, okB, okC;

    LOADP(0, vaA, vbA, okA);
    LOADP(1, vaB, vbB, okB);
    for (int i = t; i < 3 * 16 * 85; i += 192) (&corr_lds[0][0][0])[i] = 0.f;
    __syncthreads();                     // one full drain at loop entry is fine

    // ---- 11 phases; counted-vmcnt barriers (NO vmcnt drain in the loop) ----
#define PHASE(p, VA, VB, OK, LP, NVA, NVB, NOK)                              \
    do {                                                                     \
        if (OK) WRITEP(VA, VB);                                              \
        asm volatile("s_waitcnt lgkmcnt(0)" ::: "memory");                   \
        __builtin_amdgcn_s_barrier();                                        \
        __builtin_amdgcn_sched_barrier(0);                                   \
        if (LP <= 10) LOADP(LP, NVA, NVB, NOK);                              \
        const int dyi = (p) - ry;                                            \
        if (OK && dyi >= 0 && dyi <= 8) COMPUTE(dyi);                        \
        asm volatile("s_waitcnt lgkmcnt(0)" ::: "memory");                   \
        __builtin_amdgcn_s_barrier();                                        \
        __builtin_amdgcn_sched_barrier(0);                                   \
    } while (0)

    PHASE(0, vaA, vbA, okA, 2, vaC, vbC, okC);
    PHASE(1, vaB, vbB, okB, 3, vaA, vbA, okA);
    PHASE(2, vaC, vbC, okC, 4, vaB, vbB, okB);
    PHASE(3, vaA, vbA, okA, 5, vaC, vbC, okC);
    PHASE(4, vaB, vbB, okB, 6, vaA, vbA, okA);
    PHASE(5, vaC, vbC, okC, 7, vaB, vbB, okB);
    PHASE(6, vaA, vbA, okA, 8, vaC, vbC, okC);
    PHASE(7, vaB, vbB, okB, 9, vaA, vbA, okA);
    PHASE(8, vaC, vbC, okC, 10, vaB, vbB, okB);
    PHASE(9, vaA, vbA, okA, 11, vaC, vbC, okC);   // LP=11 > 10: no load
    PHASE(10, vaB, vbB, okB, 11, vaC, vbC, okC);
#undef PHASE

    // ---- softmax pass 1 (verified): pxi = t%48, part = t/48 ----
    {
        const int pxi = t % 48;
        const int part = t / 48;
        const int sry = pxi >> 4, spx = pxi & 15;
        float pm = -1e30f;
        for (int k = part; k < K_; k += 4)
            pm = fmaxf(pm, corr_lds[sry][spx][k]);      // scale already folded
        pmax[part][pxi] = pm;
        __syncthreads();
        const float m = fmaxf(fmaxf(pmax[0][pxi], pmax[1][pxi]),
                              fmaxf(pmax[2][pxi], pmax[3][pxi]));
        float ps = 0.f, pfx = 0.f, pfy = 0.f;
        for (int k = part; k < K_; k += 4) {
            const float e = __expf(corr_lds[sry][spx][k] - m);
            corr_lds[sry][spx][k] = e;                  // cache exp for pass 2
            ps += e;
            pfx += e * (float)(k % 9 - 4);
            pfy += e * (float)(k / 9 - 4);
        }
        psum[part][pxi] = ps; pfxb[part][pxi] = pfx; pfyb[part][pxi] = pfy;
        __syncthreads();
        if (t < 48) {
            const float s = psum[0][t] + psum[1][t] + psum[2][t] + psum[3][t];
            const float inv = 1.f / s;
            ibuf[t] = inv;
            const float fx = pfxb[0][t] + pfxb[1][t] + pfxb[2][t] + pfxb[3][t];
            const float fy = pfyb[0][t] + pfyb[1][t] + pfyb[2][t] + pfyb[3][t];
            const int yy = y0 + (t >> 4);
            const int x = px0 + (t & 15);
            out[((size_t)(b * 2 + 0) * H_ + yy) * W_ + x] = fx * inv;
            out[((size_t)(b * 2 + 1) * H_ + yy) * W_ + x] = fy * inv;
        }
    }
    __syncthreads();

    // ---- pass 2: match_prob = cached exp * inv (coalesced) ----
    float* outp = out + FLOW_ELEMS;
    for (int f = t; f < 48 * K_; f += 192) {
        const int pxi = f / K_;
        const int k = f - pxi * K_;
        const int yy = y0 + (pxi >> 4);
        const int x = px0 + (pxi & 15);
        outp[((size_t)b * HW_ + (size_t)yy * W_ + x) * K_ + k] =
            corr_lds[pxi >> 4][pxi & 15][k] * ibuf[pxi];
    }
}

extern "C" void kernel_launch(void* const* d_in, const int* in_sizes, int n_in,
                              void* d_out, int out_size, void* d_ws, size_t ws_size,
                              hipStream_t stream) {
    (void)in_sizes; (void)n_in; (void)out_size; (void)d_ws; (void)ws_size;
    const float* f0 = (const float*)d_in[0];
    const float* f1 = (const float*)d_in[1];
    float* out = (float*)d_out;

    fused_kernel<<<512, 192, 0, stream>>>(f0, f1, out);
}

// Round 28
// 22.377 us; speedup vs baseline: 1.0360x; 1.0360x over previous
//
#include <hip/hip_runtime.h>
#include <math.h>

#define W_ 128
#define H_ 96
#define C_ 128
#define HW_ (H_ * W_)          // 12288
#define K_ 81
#define FLOW_ELEMS (2 * 2 * H_ * W_)   // 49152
#define TCOLS 32               // tile cols allocated; 24 staged (cols 24..31 unused)
#define TSTR 68                // u32 stride per col; 272 B -> 16B-aligned b128 reads

typedef __fp16 f16x8 __attribute__((ext_vector_type(8)));
typedef float  f32x4 __attribute__((ext_vector_type(4)));

__device__ __forceinline__ unsigned pack_pair(float a, float b) {
    return __builtin_bit_cast(unsigned, __builtin_amdgcn_cvt_pkrtz(a, b));
}

// Round 28: CHAMPION RESTORED (R26 verbatim, 22.42 us) -- R27's counted-vmcnt
// variant regressed slightly and is reverted. Structure: 512 blocks = 2/CU
// (balanced, XCD-swizzled); block = 192 thr = 3 waves = rows y0..y0+2 of one
// 16-px tile; 11 phases stage halo rows y0-4..y0+6 once each (24 cols x 128 ch
// f16 pairs), 2-deep register prefetch (3-set A/B/C rotation); COMPUTE = 8x
// mfma_f32_16x16x32_f16 from b128-aligned LDS (TSTR=68) + band extract;
// folded-scale parallel softmax with exp-caching; coalesced writeouts.
__global__ __launch_bounds__(192) void fused_kernel(const float* __restrict__ f0,
                                                    const float* __restrict__ f1,
                                                    float* __restrict__ out) {
    __shared__ unsigned tile[TCOLS * TSTR];          // 8704 B (cols 24..31 unwritten)
    __shared__ float corr_lds[3][16][85];            // 16320 B
    __shared__ float pmax[4][49], psum[4][49], pfxb[4][49], pfyb[4][49];
    __shared__ float ibuf[48];

    const int t = threadIdx.x;
    const int ry = t >> 6, l = t & 63;   // wave id == output row within strip
    const int L = (blockIdx.x & 7) * 64 + (blockIdx.x >> 3);   // 512 = 8*64
    const int b = L >> 8;
    const int rem = L & 255;
    const int ys = rem >> 3, xq = rem & 7;
    const int y0 = ys * 3;               // rows y0, y0+1, y0+2
    const int px0 = xq * 16;             // 16-px tile base

    // ---- staging slots: exactly 2/thread; s = i*192+t: cp = s/6, quad q = s%6 ----
    int g_off[2], lds_w[2];
    bool g_ok[2];
#pragma unroll
    for (int i = 0; i < 2; ++i) {
        const int s = i * 192 + t;
        const int cp = s / 6;
        const int q = s - cp * 6;
        const int x0 = px0 + 4 * q - 4;
        g_ok[i] = (x0 >= 0) && (x0 <= 124);
        g_off[i] = 2 * cp * HW_ + (g_ok[i] ? x0 : 0);
        lds_w[i] = (4 * q) * TSTR + cp;
    }
    const float* f1base = f1 + (size_t)b * C_ * HW_;

    // ---- A-frags (R14-verified layout), row y0+ry, scale folded ----
    const float scale = 0.08838834764831845f;   // 1/sqrt(128)
    f16x8 a[4];
    {
        const float* f0p = f0 + (size_t)b * C_ * HW_ + (size_t)(y0 + ry) * W_
                              + px0 + (l & 15);
#pragma unroll
        for (int kk = 0; kk < 4; ++kk) {
            f16x8 av;
#pragma unroll
            for (int j = 0; j < 8; ++j)
                av[j] = (__fp16)(f0p[(size_t)(kk * 32 + (l >> 4) * 8 + j) * HW_] * scale);
            a[kk] = av;
        }
    }

    // ---- helpers (verified patterns) ----
    auto LOADP = [&](int p, float4 (&va)[2], float4 (&vb)[2], bool& ok) {
        const int r = y0 - 4 + p;
        ok = (r >= 0) && (r < H_);
        const float* f1b = f1base + (size_t)(ok ? r : 0) * W_;
#pragma unroll
        for (int i = 0; i < 2; ++i) {
            float4 x = {0.f, 0.f, 0.f, 0.f}, y = {0.f, 0.f, 0.f, 0.f};
            if (ok && g_ok[i]) {
                x = *(const float4*)(f1b + g_off[i]);
                y = *(const float4*)(f1b + g_off[i] + HW_);
            }
            va[i] = x; vb[i] = y;
        }
    };
    auto WRITEP = [&](const float4 (&va)[2], const float4 (&vb)[2]) {
#pragma unroll
        for (int i = 0; i < 2; ++i) {
            tile[lds_w[i]]            = pack_pair(va[i].x, vb[i].x);
            tile[lds_w[i] + TSTR]     = pack_pair(va[i].y, vb[i].y);
            tile[lds_w[i] + 2 * TSTR] = pack_pair(va[i].z, vb[i].z);
            tile[lds_w[i] + 3 * TSTR] = pack_pair(va[i].w, vb[i].w);
        }
    };
    auto COMPUTE = [&](int dyi) {        // dyi = p - ry in [0,8]
        f32x4 accA = {0.f, 0.f, 0.f, 0.f}, accB = {0.f, 0.f, 0.f, 0.f};
#pragma unroll
        for (int kk = 0; kk < 4; ++kk) {
            const int off = kk * 16 + (l >> 4) * 4;
            {
                const int col = l & 15;
                const uint4 u = *(const uint4*)&tile[col * TSTR + off];  // b128
                accA = __builtin_amdgcn_mfma_f32_16x16x32_f16(
                    a[kk], __builtin_bit_cast(f16x8, u), accA, 0, 0, 0);
            }
            {
                const int col = 16 + (l & 15);   // cols 24..31: outputs discarded
                const uint4 u = *(const uint4*)&tile[col * TSTR + off];  // b128
                accB = __builtin_amdgcn_mfma_f32_16x16x32_f16(
                    a[kk], __builtin_bit_cast(f16x8, u), accB, 0, 0, 0);
            }
        }
        // band extract (R14-verified): dx = j2 - i2 in [0,8]
#pragma unroll
        for (int h = 0; h < 2; ++h) {
            const f32x4 acc = h ? accB : accA;
#pragma unroll
            for (int rg = 0; rg < 4; ++rg) {
                const int i2 = (l >> 4) * 4 + rg;
                const int j2 = h * 16 + (l & 15);
                const int dxw = j2 - i2;
                if (dxw >= 0 && dxw <= 8)
                    corr_lds[ry][i2][dyi * 9 + dxw] = acc[rg];
            }
        }
    };

    float4 vaA[2], vbA[2], vaB[2], vbB[2], vaC[2], vbC[2];
    bool okA, okB, okC;

    LOADP(0, vaA, vbA, okA);
    LOADP(1, vaB, vbB, okB);
    for (int i = t; i < 3 * 16 * 85; i += 192) (&corr_lds[0][0][0])[i] = 0.f;
    __syncthreads();

    // ---- 11 phases, sets A,B,C rotation; load p+2 during p (verified) ----
#define PHASE(p, VA, VB, OK, LP, NVA, NVB, NOK)                              \
    do {                                                                     \
        if (OK) WRITEP(VA, VB);                                              \
        __syncthreads();                                                     \
        if (LP <= 10) LOADP(LP, NVA, NVB, NOK);                              \
        const int dyi = (p) - ry;                                            \
        if (OK && dyi >= 0 && dyi <= 8) COMPUTE(dyi);                        \
        __syncthreads();                                                     \
    } while (0)

    PHASE(0, vaA, vbA, okA, 2, vaC, vbC, okC);
    PHASE(1, vaB, vbB, okB, 3, vaA, vbA, okA);
    PHASE(2, vaC, vbC, okC, 4, vaB, vbB, okB);
    PHASE(3, vaA, vbA, okA, 5, vaC, vbC, okC);
    PHASE(4, vaB, vbB, okB, 6, vaA, vbA, okA);
    PHASE(5, vaC, vbC, okC, 7, vaB, vbB, okB);
    PHASE(6, vaA, vbA, okA, 8, vaC, vbC, okC);
    PHASE(7, vaB, vbB, okB, 9, vaA, vbA, okA);
    PHASE(8, vaC, vbC, okC, 10, vaB, vbB, okB);
    PHASE(9, vaA, vbA, okA, 11, vaC, vbC, okC);   // LP=11 > 10: no load
    PHASE(10, vaB, vbB, okB, 11, vaC, vbC, okC);
#undef PHASE

    // ---- softmax pass 1 (verified): pxi = t%48, part = t/48 ----
    {
        const int pxi = t % 48;
        const int part = t / 48;
        const int sry = pxi >> 4, spx = pxi & 15;
        float pm = -1e30f;
        for (int k = part; k < K_; k += 4)
            pm = fmaxf(pm, corr_lds[sry][spx][k]);      // scale already folded
        pmax[part][pxi] = pm;
        __syncthreads();
        const float m = fmaxf(fmaxf(pmax[0][pxi], pmax[1][pxi]),
                              fmaxf(pmax[2][pxi], pmax[3][pxi]));
        float ps = 0.f, pfx = 0.f, pfy = 0.f;
        for (int k = part; k < K_; k += 4) {
            const float e = __expf(corr_lds[sry][spx][k] - m);
            corr_lds[sry][spx][k] = e;                  // cache exp for pass 2
            ps += e;
            pfx += e * (float)(k % 9 - 4);
            pfy += e * (float)(k / 9 - 4);
        }
        psum[part][pxi] = ps; pfxb[part][pxi] = pfx; pfyb[part][pxi] = pfy;
        __syncthreads();
        if (t < 48) {
            const float s = psum[0][t] + psum[1][t] + psum[2][t] + psum[3][t];
            const float inv = 1.f / s;
            ibuf[t] = inv;
            const float fx = pfxb[0][t] + pfxb[1][t] + pfxb[2][t] + pfxb[3][t];
            const float fy = pfyb[0][t] + pfyb[1][t] + pfyb[2][t] + pfyb[3][t];
            const int yy = y0 + (t >> 4);
            const int x = px0 + (t & 15);
            out[((size_t)(b * 2 + 0) * H_ + yy) * W_ + x] = fx * inv;
            out[((size_t)(b * 2 + 1) * H_ + yy) * W_ + x] = fy * inv;
        }
    }
    __syncthreads();

    // ---- pass 2: match_prob = cached exp * inv (coalesced) ----
    float* outp = out + FLOW_ELEMS;
    for (int f = t; f < 48 * K_; f += 192) {
        const int pxi = f / K_;
        const int k = f - pxi * K_;
        const int yy = y0 + (pxi >> 4);
        const int x = px0 + (pxi & 15);
        outp[((size_t)b * HW_ + (size_t)yy * W_ + x) * K_ + k] =
            corr_lds[pxi >> 4][pxi & 15][k] * ibuf[pxi];
    }
}

extern "C" void kernel_launch(void* const* d_in, const int* in_sizes, int n_in,
                              void* d_out, int out_size, void* d_ws, size_t ws_size,
                              hipStream_t stream) {
    (void)in_sizes; (void)n_in; (void)out_size; (void)d_ws; (void)ws_size;
    const float* f0 = (const float*)d_in[0];
    const float* f1 = (const float*)d_in[1];
    float* out = (float*)d_out;

    fused_kernel<<<512, 192, 0, stream>>>(f0, f1, out);
}